// Round 5
// baseline (296.006 us; speedup 1.0000x reference)
//
#include <hip/hip_runtime.h>
#include <math.h>

#define N_NODES 30000
#define E_EDGES 480000
#define EP (E_EDGES + N_NODES) /* 510000 edges incl self loops */
#define IN_CH 128
#define HID 32
#define HEADS 8
#define HC 256
#define BN_EPS 1e-5f
#define NEG_SLOPE 0.2f
#define SCAN_NB ((N_NODES + 1023) / 1024) /* 30 */
#define PART_SLOTS 64 /* BN partial accumulation slots (x512 floats) */
#define M_PAD 30080   /* row padding so gload_lds tail reads stay in mapped ws */

typedef __attribute__((ext_vector_type(8))) short bf16x8;
typedef __attribute__((ext_vector_type(4))) float f32x4;

__device__ __forceinline__ float elu_f(float x) { return x > 0.f ? x : __expf(x) - 1.f; }
__device__ __forceinline__ float lrelu_f(float x) { return x >= 0.f ? x : NEG_SLOPE * x; }
__device__ __forceinline__ float bf2f(unsigned short u) {
    return __uint_as_float(((unsigned)u) << 16);
}
__device__ __forceinline__ unsigned short f2bf(float f) {
    unsigned u = __float_as_uint(f);
    return (unsigned short)((u + 0x7fffu + ((u >> 16) & 1u)) >> 16);
}

#define GLD16(gp, lp)                                                      \
    __builtin_amdgcn_global_load_lds(                                      \
        (const __attribute__((address_space(1))) unsigned int*)(gp),       \
        (__attribute__((address_space(3))) unsigned int*)(lp), 16, 0, 0)

// ---------------- W1 fp32 -> bf16 transposed ----------------
__global__ void wt_all_kernel(const float* __restrict__ W1,
                              unsigned short* __restrict__ wt1) {
    int i = blockIdx.x * 256 + threadIdx.x;
    if (i < IN_CH * HC) {
        int k = i >> 8, n = i & 255;
        wt1[(size_t)n * IN_CH + k] = f2bf(W1[i]);
    }
}

// ---------------- x fp32 -> bf16 (one-time, vectorized) ----------------
__global__ void xconv_kernel(const float* __restrict__ x, unsigned short* __restrict__ xbf) {
    int i = blockIdx.x * 256 + threadIdx.x;
    if (i * 8 >= N_NODES * IN_CH) return;
    const float4* xp = (const float4*)(x + (size_t)i * 8);
    float4 v0 = xp[0], v1 = xp[1];
    ushort4 o0, o1;
    o0.x = f2bf(v0.x); o0.y = f2bf(v0.y); o0.z = f2bf(v0.z); o0.w = f2bf(v0.w);
    o1.x = f2bf(v1.x); o1.y = f2bf(v1.y); o1.z = f2bf(v1.z); o1.w = f2bf(v1.w);
    ushort4* op = (ushort4*)(xbf + (size_t)i * 8);
    op[0] = o0; op[1] = o1;
}

// ---------------- BN fold into weights: layer-2 GEMM ----------------
// BN(A)*W2 = A*(sc o W2) + (sh . W2): wt2p[n][k] = bf16(W2[k][n]*sc[k]),
// cb2[n] = sum_k sh[k]*W2[k][n]. One block per n.
__global__ __launch_bounds__(256) void fold2_kernel(const float* __restrict__ W2,
                                                    const float* __restrict__ part,
                                                    const float* __restrict__ g,
                                                    const float* __restrict__ be,
                                                    unsigned short* __restrict__ wt2p,
                                                    float* __restrict__ cb2) {
    __shared__ float red[256];
    int n = blockIdx.x, k = threadIdx.x;
    float s = 0.f, qq = 0.f;
#pragma unroll
    for (int b = 0; b < PART_SLOTS; ++b) {
        s += part[(size_t)b * 512 + k];
        qq += part[(size_t)b * 512 + 256 + k];
    }
    float mn = s / (float)N_NODES;
    float var = qq / (float)N_NODES - mn * mn;
    float istd = rsqrtf(var + BN_EPS);
    float sck = istd * g[k];
    float shk = be[k] - mn * sck;
    float w = W2[(size_t)k * HC + n];
    wt2p[(size_t)n * HC + k] = f2bf(w * sck);
    red[k] = shk * w;
    __syncthreads();
    for (int off = 128; off > 0; off >>= 1) {
        if (k < off) red[k] += red[k + off];
        __syncthreads();
    }
    if (k == 0) cb2[n] = red[0];
}

// ---------------- BN fold into MLP weights ----------------
// wtmp[n][k] = bf16(lW1[k][n]*sc2[k]); lb1p[n] = lb1[n] + sum_k sh2[k]*lW1[k][n].
__global__ __launch_bounds__(256) void fold3_kernel(const float* __restrict__ lW1,
                                                    const float* __restrict__ part,
                                                    const float* __restrict__ g,
                                                    const float* __restrict__ be,
                                                    const float* __restrict__ lb1,
                                                    unsigned short* __restrict__ wtmp,
                                                    float* __restrict__ lb1p) {
    __shared__ float red[256];
    int n = blockIdx.x, k = threadIdx.x;
    float s = 0.f, qq = 0.f;
#pragma unroll
    for (int b = 0; b < PART_SLOTS; ++b) {
        s += part[(size_t)b * 512 + k];
        qq += part[(size_t)b * 512 + 256 + k];
    }
    float mn = s / (float)N_NODES;
    float var = qq / (float)N_NODES - mn * mn;
    float istd = rsqrtf(var + BN_EPS);
    float sck = istd * g[k];
    float shk = be[k] - mn * sck;
    float w = lW1[(size_t)k * HID + n];
    wtmp[(size_t)n * HC + k] = f2bf(w * sck);
    red[k] = shk * w;
    __syncthreads();
    for (int off = 128; off > 0; off >>= 1) {
        if (k < off) red[k] += red[k + off];
        __syncthreads();
    }
    if (k == 0) lb1p[n] = lb1[n] + red[0];
}

// ---------------- pure-bf16 MFMA GEMM via global_load_lds + fused al epilogue ---------
// C[M,256] = A[M,K]*Wt^T + cb. 512 thr = 8 waves (2M x 4N); tile 128x256, BK=32.
// Staging: 3 global_load_lds_dwordx4 per wave per K-step, ZERO VALU transforms
// (BN is pre-folded into Wt/cb). LDS linear (gload_lds requirement) with XOR
// chunk swizzle cc ^= (row&3)^((row>>2)&3) applied on BOTH the per-lane global
// source addr and the ds_read offset (rule: both-sides-or-neither) -> 2-way bank
// alias only (free).
__global__ __launch_bounds__(512) void gemm_mfma(const unsigned short* __restrict__ Abf,
                                                 const unsigned short* __restrict__ Bt,
                                                 const float* __restrict__ cb,
                                                 unsigned short* __restrict__ C,
                                                 float* __restrict__ al_s,
                                                 float* __restrict__ al_d,
                                                 const float* __restrict__ a_src,
                                                 const float* __restrict__ a_dst,
                                                 int M, int K) {
    __shared__ __align__(16) unsigned short As[128 * 32];
    __shared__ __align__(16) unsigned short Bs[256 * 32];
    int tid = threadIdx.x;
    int wave = tid >> 6, lane = tid & 63;
    int m = lane & 15, q = lane >> 4;
    int wr = (wave >> 2) * 64;  /* wave row offset in tile */
    int hp = wave & 3;          /* head-pair / col group   */
    int col0 = hp * 64;
    int row0 = blockIdx.x * 128;

    /* staging source/dest (per-lane global addr carries the swizzle) */
    int sA = wave * 64 + lane;
    int rA = sA >> 2, scA = sA & 3;
    int ccA = scA ^ (rA & 3) ^ ((rA >> 2) & 3);
    const unsigned short* aSrc = Abf + (size_t)(row0 + rA) * K + ccA * 8;
    unsigned short* aDst = As + wave * 512;
    int sB0 = wave * 128 + lane;
    int rB0 = sB0 >> 2, scB0 = sB0 & 3;
    int ccB0 = scB0 ^ (rB0 & 3) ^ ((rB0 >> 2) & 3);
    const unsigned short* bSrc0 = Bt + (size_t)rB0 * K + ccB0 * 8;
    unsigned short* bDst0 = Bs + wave * 1024;
    int sB1 = sB0 + 64;
    int rB1 = sB1 >> 2, scB1 = sB1 & 3;
    int ccB1 = scB1 ^ (rB1 & 3) ^ ((rB1 >> 2) & 3);
    const unsigned short* bSrc1 = Bt + (size_t)rB1 * K + ccB1 * 8;
    unsigned short* bDst1 = Bs + wave * 1024 + 512;

    int ccr8 = (q ^ (m & 3) ^ ((m >> 2) & 3)) * 8; /* read-side swizzled chunk */

    f32x4 acc[4][4];
#pragma unroll
    for (int i = 0; i < 4; ++i)
#pragma unroll
        for (int j = 0; j < 4; ++j) acc[i][j] = (f32x4){0.f, 0.f, 0.f, 0.f};

    for (int k0 = 0; k0 < K; k0 += 32) {
        GLD16(aSrc + k0, aDst);
        GLD16(bSrc0 + k0, bDst0);
        GLD16(bSrc1 + k0, bDst1);
        __syncthreads();
        bf16x8 a0 = *(const bf16x8*)(As + (wr + m) * 32 + ccr8);
        bf16x8 a1 = *(const bf16x8*)(As + (wr + 16 + m) * 32 + ccr8);
        bf16x8 a2 = *(const bf16x8*)(As + (wr + 32 + m) * 32 + ccr8);
        bf16x8 a3 = *(const bf16x8*)(As + (wr + 48 + m) * 32 + ccr8);
#pragma unroll
        for (int ni = 0; ni < 4; ++ni) {
            bf16x8 b = *(const bf16x8*)(Bs + (col0 + ni * 16 + m) * 32 + ccr8);
            acc[0][ni] = __builtin_amdgcn_mfma_f32_16x16x32_bf16(a0, b, acc[0][ni], 0, 0, 0);
            acc[1][ni] = __builtin_amdgcn_mfma_f32_16x16x32_bf16(a1, b, acc[1][ni], 0, 0, 0);
            acc[2][ni] = __builtin_amdgcn_mfma_f32_16x16x32_bf16(a2, b, acc[2][ni], 0, 0, 0);
            acc[3][ni] = __builtin_amdgcn_mfma_f32_16x16x32_bf16(a3, b, acc[3][ni], 0, 0, 0);
        }
        __syncthreads();
    }
    /* fold in the column bias (BN shift term); logits then see the full h */
    float cbv[4];
#pragma unroll
    for (int ni = 0; ni < 4; ++ni) cbv[ni] = cb[col0 + ni * 16 + m];
#pragma unroll
    for (int mi = 0; mi < 4; ++mi)
#pragma unroll
        for (int ni = 0; ni < 4; ++ni)
#pragma unroll
            for (int r = 0; r < 4; ++r) acc[mi][ni][r] += cbv[ni];

    // ---- epilogue: C store + per-head logits (col group hp -> heads 2hp, 2hp+1) ----
    float asv[4], adv[4];
#pragma unroll
    for (int ni = 0; ni < 4; ++ni) {
        asv[ni] = a_src[col0 + ni * 16 + m];
        adv[ni] = a_dst[col0 + ni * 16 + m];
    }
#pragma unroll
    for (int mi = 0; mi < 4; ++mi) {
#pragma unroll
        for (int r = 0; r < 4; ++r) {
            int grow = row0 + wr + mi * 16 + q * 4 + r;
            bool gv = grow < M;
            if (gv) {
#pragma unroll
                for (int ni = 0; ni < 4; ++ni)
                    C[(size_t)grow * HC + col0 + ni * 16 + m] = f2bf(acc[mi][ni][r]);
            }
            float ps0 = acc[mi][0][r] * asv[0] + acc[mi][1][r] * asv[1];
            float pd0 = acc[mi][0][r] * adv[0] + acc[mi][1][r] * adv[1];
            float ps1 = acc[mi][2][r] * asv[2] + acc[mi][3][r] * asv[3];
            float pd1 = acc[mi][2][r] * adv[2] + acc[mi][3][r] * adv[3];
            ps0 += __shfl_xor(ps0, 1); pd0 += __shfl_xor(pd0, 1);
            ps1 += __shfl_xor(ps1, 1); pd1 += __shfl_xor(pd1, 1);
            ps0 += __shfl_xor(ps0, 2); pd0 += __shfl_xor(pd0, 2);
            ps1 += __shfl_xor(ps1, 2); pd1 += __shfl_xor(pd1, 2);
            ps0 += __shfl_xor(ps0, 4); pd0 += __shfl_xor(pd0, 4);
            ps1 += __shfl_xor(ps1, 4); pd1 += __shfl_xor(pd1, 4);
            ps0 += __shfl_xor(ps0, 8); pd0 += __shfl_xor(pd0, 8);
            ps1 += __shfl_xor(ps1, 8); pd1 += __shfl_xor(pd1, 8);
            if (gv) {
                if (m == 0) {
                    al_s[grow * HEADS + 2 * hp] = ps0;
                    al_d[grow * HEADS + 2 * hp] = pd0;
                } else if (m == 1) {
                    al_s[grow * HEADS + 2 * hp + 1] = ps1;
                    al_d[grow * HEADS + 2 * hp + 1] = pd1;
                }
            }
        }
    }
}

// ---------------- CSR build (by dst) ----------------
// Also zeroes the BN partial-sum slots + cb0 to save dispatches.
__global__ void deg_kernel(const int* __restrict__ ei, int* __restrict__ deg,
                           float* __restrict__ part) {
    int e = blockIdx.x * blockDim.x + threadIdx.x;
    if (e < 2 * PART_SLOTS * 512 + 256) part[e] = 0.f;
    if (e >= EP) return;
    int d = (e < E_EDGES) ? ei[E_EDGES + e] : e - E_EDGES;
    atomicAdd(deg + d, 1);
}

__global__ __launch_bounds__(1024) void scan_blk(const int* __restrict__ deg,
                                                 int* __restrict__ rs,
                                                 int* __restrict__ bsum) {
    __shared__ int sh[1024];
    int t = threadIdx.x;
    int i = blockIdx.x * 1024 + t;
    int v = (i < N_NODES) ? deg[i] : 0;
    sh[t] = v;
    __syncthreads();
    for (int off = 1; off < 1024; off <<= 1) {
        int tv = (t >= off) ? sh[t - off] : 0;
        __syncthreads();
        sh[t] += tv;
        __syncthreads();
    }
    if (i < N_NODES) rs[i] = sh[t] - v;
    if (t == 1023) bsum[blockIdx.x] = sh[1023];
}

// scan_add with the top-level (30-entry) scan folded in.
__global__ __launch_bounds__(1024) void scan_add(int* __restrict__ rs,
                                                 int* __restrict__ cursor,
                                                 const int* __restrict__ bsum) {
    __shared__ int sh_off, sh_tot;
    int t = threadIdx.x;
    if (t < 64) {
        int v = (t < SCAN_NB) ? bsum[t] : 0;
        int pre = (t < (int)blockIdx.x) ? v : 0;
        int tot = v;
#pragma unroll
        for (int off = 1; off < 64; off <<= 1) {
            tot += __shfl_xor(tot, off);
            pre += __shfl_xor(pre, off);
        }
        if (t == 0) { sh_off = pre; sh_tot = tot; }
    }
    __syncthreads();
    int i = blockIdx.x * 1024 + t;
    if (i < N_NODES) {
        int v = rs[i] + sh_off;
        rs[i] = v;
        cursor[i] = v;
    } else if (i == N_NODES) {
        rs[N_NODES] = sh_tot;
    }
}

__global__ void scatter_kernel(const int* __restrict__ ei, int* __restrict__ cursor,
                               int* __restrict__ csr_src) {
    int e = blockIdx.x * blockDim.x + threadIdx.x;
    if (e >= EP) return;
    int s, d;
    if (e < E_EDGES) { s = ei[e]; d = ei[E_EDGES + e]; } else { s = d = e - E_EDGES; }
    int pos = atomicAdd(cursor + d, 1);
    csr_src[pos] = s;
}

// ---------------- fused softmax + aggregation + bias + ELU + BN stats ----------------
// R1-verified structure (47 us; best measured). 8 edges/iter, paired 16B/lane
// gathers; do NOT deepen (R4: 16-edge -> VGPR 48, occupancy -44%, 51 us) and do
// NOT split channels (R2: killed MLP, 88 us).
__global__ __launch_bounds__(256) void attn_kernel(const uint4* __restrict__ h8,
                                                   const float* __restrict__ al_s,
                                                   const float* __restrict__ al_d,
                                                   const int* __restrict__ row_start,
                                                   const int* __restrict__ csr_src,
                                                   const float4* __restrict__ bias4,
                                                   uint4* __restrict__ out8,
                                                   float* __restrict__ part) {
    __shared__ float lds_s[4][256];
    __shared__ float lds_q[4][256];
    int wave = threadIdx.x >> 6;
    int d = blockIdx.x * 4 + wave;
    int lane = threadIdx.x & 63;
    int hh = lane & 7, eo = lane >> 3;     // logit lanes: edge eo, head hh
    int g = lane >> 5, c = lane & 31;      // agg lanes: parity g, uint4-chunk c
    int hl = c >> 2;                       // head owning channels 8c..8c+7
    int beg = row_start[d], end = row_start[d + 1];
    float ad = al_d[d * HEADS + hh];
    float ssum = 0.f;
    float acc[8];
#pragma unroll
    for (int t = 0; t < 8; ++t) acc[t] = 0.f;

#define PAIR_BODY(p)                                                      \
    {                                                                     \
        int e0 = 2 * (p) + g;                                             \
        int sj = __shfl(sreg, e0 * 8);                                    \
        float aj = __shfl(ex, e0 * 8 + hl);                               \
        uint4 v = h8[(size_t)sj * 32 + c];                                \
        acc[0] += aj * bf2f((unsigned short)v.x);                         \
        acc[1] += aj * bf2f((unsigned short)(v.x >> 16));                 \
        acc[2] += aj * bf2f((unsigned short)v.y);                         \
        acc[3] += aj * bf2f((unsigned short)(v.y >> 16));                 \
        acc[4] += aj * bf2f((unsigned short)v.z);                         \
        acc[5] += aj * bf2f((unsigned short)(v.z >> 16));                 \
        acc[6] += aj * bf2f((unsigned short)v.w);                         \
        acc[7] += aj * bf2f((unsigned short)(v.w >> 16));                 \
    }

    for (int i = beg; i < end; i += 8) {
        int chunk = end - i;
        if (chunk > 8) chunk = 8;
        int sreg = 0;
        float ex = 0.f;
        if (eo < chunk) {
            sreg = csr_src[i + eo];
            ex = __expf(lrelu_f(al_s[sreg * HEADS + hh] + ad));
        }
        ssum += ex;
        if (chunk == 8) {
#pragma unroll
            for (int p = 0; p < 4; ++p) PAIR_BODY(p);
        } else {
            int np = (chunk + 1) >> 1;  // odd tail: g=1 lane reads ex=0 -> no-op
            for (int p = 0; p < np; ++p) PAIR_BODY(p);
        }
    }
#undef PAIR_BODY

    // combine edge-parity halves; both halves end with identical acc
#pragma unroll
    for (int t = 0; t < 8; ++t) acc[t] += __shfl_xor(acc[t], 32);
    ssum += __shfl_xor(ssum, 8);
    ssum += __shfl_xor(ssum, 16);
    ssum += __shfl_xor(ssum, 32);
    float inv = 1.f / __shfl(ssum, hl);

    float4 b0 = bias4[c * 2], b1 = bias4[c * 2 + 1];
    float o0 = elu_f(acc[0] * inv + b0.x);
    float o1 = elu_f(acc[1] * inv + b0.y);
    float o2 = elu_f(acc[2] * inv + b0.z);
    float o3 = elu_f(acc[3] * inv + b0.w);
    float o4 = elu_f(acc[4] * inv + b1.x);
    float o5 = elu_f(acc[5] * inv + b1.y);
    float o6 = elu_f(acc[6] * inv + b1.z);
    float o7 = elu_f(acc[7] * inv + b1.w);

    if (g == 0) {
        uint4 ov;
        ov.x = (unsigned)f2bf(o0) | ((unsigned)f2bf(o1) << 16);
        ov.y = (unsigned)f2bf(o2) | ((unsigned)f2bf(o3) << 16);
        ov.z = (unsigned)f2bf(o4) | ((unsigned)f2bf(o5) << 16);
        ov.w = (unsigned)f2bf(o6) | ((unsigned)f2bf(o7) << 16);
        out8[(size_t)d * 32 + c] = ov;
        int cb = c * 8;
        lds_s[wave][cb + 0] = o0; lds_q[wave][cb + 0] = o0 * o0;
        lds_s[wave][cb + 1] = o1; lds_q[wave][cb + 1] = o1 * o1;
        lds_s[wave][cb + 2] = o2; lds_q[wave][cb + 2] = o2 * o2;
        lds_s[wave][cb + 3] = o3; lds_q[wave][cb + 3] = o3 * o3;
        lds_s[wave][cb + 4] = o4; lds_q[wave][cb + 4] = o4 * o4;
        lds_s[wave][cb + 5] = o5; lds_q[wave][cb + 5] = o5 * o5;
        lds_s[wave][cb + 6] = o6; lds_q[wave][cb + 6] = o6 * o6;
        lds_s[wave][cb + 7] = o7; lds_q[wave][cb + 7] = o7 * o7;
    }
    __syncthreads();
    int ch = threadIdx.x;
    float s = lds_s[0][ch] + lds_s[1][ch] + lds_s[2][ch] + lds_s[3][ch];
    float q = lds_q[0][ch] + lds_q[1][ch] + lds_q[2][ch] + lds_q[3][ch];
    float* pb = part + (size_t)(blockIdx.x & (PART_SLOTS - 1)) * 512;
    atomicAdd(pb + ch, s);
    atomicAdd(pb + 256 + ch, q);
}

// ---------------- MLP head via MFMA (pure bf16, BN pre-folded) ----------------
__global__ __launch_bounds__(256) void mlp_mfma(const unsigned short* __restrict__ in,
                                                const unsigned short* __restrict__ Wt,
                                                const float* __restrict__ lb1p,
                                                const float* __restrict__ lW2,
                                                const float* __restrict__ lb2,
                                                float* __restrict__ out) {
    int tid = threadIdx.x;
    int wave = tid >> 6, lane = tid & 63;
    int m = lane & 15, q = lane >> 4;
    int rbase = blockIdx.x * 64 + wave * 16;
    int arow = rbase + m;
    bool valid = arow < N_NODES;
    const unsigned short* ap = in + (size_t)arow * HC;
    f32x4 acc0 = (f32x4){0.f, 0.f, 0.f, 0.f}, acc1 = acc0;
#pragma unroll
    for (int k0 = 0; k0 < HC; k0 += 32) {
        int c0 = k0 + q * 8;
        bf16x8 b0 = *(const bf16x8*)(Wt + (size_t)m * HC + c0);
        bf16x8 b1 = *(const bf16x8*)(Wt + (size_t)(m + 16) * HC + c0);
        bf16x8 a = (bf16x8){0, 0, 0, 0, 0, 0, 0, 0};
        if (valid) a = *(const bf16x8*)(ap + c0);
        acc0 = __builtin_amdgcn_mfma_f32_16x16x32_bf16(a, b0, acc0, 0, 0, 0);
        acc1 = __builtin_amdgcn_mfma_f32_16x16x32_bf16(a, b1, acc1, 0, 0, 0);
    }
    float w2a = lW2[m], w2b = lW2[m + 16];
    float ba = lb1p[m], bb = lb1p[m + 16];
#pragma unroll
    for (int r = 0; r < 4; ++r) {
        float v = elu_f(acc0[r] + ba) * w2a + elu_f(acc1[r] + bb) * w2b;
        v += __shfl_xor(v, 1);
        v += __shfl_xor(v, 2);
        v += __shfl_xor(v, 4);
        v += __shfl_xor(v, 8);
        int orow = rbase + q * 4 + r;
        if (m == 0 && orow < N_NODES) out[orow] = v + lb2[0];
    }
}

extern "C" void kernel_launch(void* const* d_in, const int* in_sizes, int n_in,
                              void* d_out, int out_size, void* d_ws, size_t ws_size,
                              hipStream_t stream) {
    const float* x   = (const float*)d_in[0];
    const int*   ei  = (const int*)d_in[1];
    const float* W1  = (const float*)d_in[2];
    const float* a1s = (const float*)d_in[3];
    const float* a1d = (const float*)d_in[4];
    const float* b1  = (const float*)d_in[5];
    const float* g1  = (const float*)d_in[6];
    const float* be1 = (const float*)d_in[7];
    const float* W2  = (const float*)d_in[8];
    const float* a2s = (const float*)d_in[9];
    const float* a2d = (const float*)d_in[10];
    const float* b2  = (const float*)d_in[11];
    const float* g2  = (const float*)d_in[12];
    const float* be2 = (const float*)d_in[13];
    const float* lW1 = (const float*)d_in[14];
    const float* lb1 = (const float*)d_in[15];
    const float* lW2 = (const float*)d_in[16];
    const float* lb2 = (const float*)d_in[17];
    float* out = (float*)d_out;

    char* p = (char*)d_ws;
    auto alloc = [&](size_t bytes) {
        char* r = p;
        p += (bytes + 255) & ~(size_t)255;
        return r;
    };
    unsigned short* x_bf  = (unsigned short*)alloc((size_t)M_PAD * IN_CH * 2);
    unsigned short* h_bf  = (unsigned short*)alloc((size_t)N_NODES * HC * 2);
    unsigned short* o_bf  = (unsigned short*)alloc((size_t)M_PAD * HC * 2);
    unsigned short* wt1   = (unsigned short*)alloc((size_t)IN_CH * HC * 2);
    unsigned short* wt2p  = (unsigned short*)alloc((size_t)HC * HC * 2);
    unsigned short* wtmp  = (unsigned short*)alloc((size_t)HC * HID * 2);
    float* f_als  = (float*)alloc((size_t)N_NODES * HEADS * 4);
    float* f_ald  = (float*)alloc((size_t)N_NODES * HEADS * 4);
    int*   i_deg  = (int*)alloc((size_t)N_NODES * 4);
    int*   i_rs   = (int*)alloc((size_t)(N_NODES + 1) * 4);
    int*   i_cur  = (int*)alloc((size_t)N_NODES * 4);
    int*   i_src  = (int*)alloc((size_t)EP * 4);
    int*   i_bsum = (int*)alloc((size_t)(SCAN_NB + 1) * 4);
    float* f_part = (float*)alloc(((size_t)2 * PART_SLOTS * 512 + 256) * 4);
    float* f_cb2  = (float*)alloc(HC * 4);
    float* f_lb1p = (float*)alloc(HID * 4);

    float* part1 = f_part;
    float* part2 = f_part + (size_t)PART_SLOTS * 512;
    float* cb0   = f_part + (size_t)2 * PART_SLOTS * 512; /* zeroed by deg_kernel */

    int eb = (EP + 255) / 256;

    // ---- CSR build (same graph both layers); deg also zeroes BN partials + cb0 ----
    hipMemsetAsync(i_deg, 0, (size_t)N_NODES * 4, stream);
    deg_kernel<<<eb, 256, 0, stream>>>(ei, i_deg, f_part);
    scan_blk<<<SCAN_NB, 1024, 0, stream>>>(i_deg, i_rs, i_bsum);
    scan_add<<<SCAN_NB, 1024, 0, stream>>>(i_rs, i_cur, i_bsum);
    scatter_kernel<<<eb, 256, 0, stream>>>(ei, i_cur, i_src);

    // ---- weight + input conversions ----
    wt_all_kernel<<<(IN_CH * HC + 255) / 256, 256, 0, stream>>>(W1, wt1);
    xconv_kernel<<<(N_NODES * IN_CH / 8 + 255) / 256, 256, 0, stream>>>(x, x_bf);

    int gblocks = (N_NODES + 127) / 128;

    // layer 1 (no BN on input; cb0 = zeros)
    gemm_mfma<<<gblocks, 512, 0, stream>>>(x_bf, wt1, cb0, h_bf, f_als, f_ald, a1s, a1d,
                                           N_NODES, IN_CH);
    attn_kernel<<<N_NODES / 4, 256, 0, stream>>>((const uint4*)h_bf, f_als, f_ald,
                                                 i_rs, i_src, (const float4*)b1,
                                                 (uint4*)o_bf, part1);
    // fold BN1 into W2 -> wt2p, cb2
    fold2_kernel<<<HC, 256, 0, stream>>>(W2, part1, g1, be1, wt2p, f_cb2);
    // layer 2 (pure bf16)
    gemm_mfma<<<gblocks, 512, 0, stream>>>(o_bf, wt2p, f_cb2, h_bf, f_als, f_ald, a2s, a2d,
                                           N_NODES, HC);
    attn_kernel<<<N_NODES / 4, 256, 0, stream>>>((const uint4*)h_bf, f_als, f_ald,
                                                 i_rs, i_src, (const float4*)b2,
                                                 (uint4*)o_bf, part2);
    // fold BN2 into lW1 -> wtmp, lb1p
    fold3_kernel<<<HID, 256, 0, stream>>>(lW1, part2, g2, be2, lb1, wtmp, f_lb1p);
    // MLP head (pure bf16)
    mlp_mfma<<<(N_NODES + 63) / 64, 256, 0, stream>>>(o_bf, wtmp, f_lb1p, lW2, lb2, out);
}